// Round 5
// baseline (66.658 us; speedup 1.0000x reference)
//
#include <hip/hip_runtime.h>

// CCM: causal 3x3 complex multi-frame filter.
// out[b,f,t,:] = sum_{i,j} (Hr+i*Hi)[b,i,j,t,f] * x[b, f+j-1, t+i-2, :]
// Hr = a0 - 0.5*(a1+a2); Hi = (sqrt(3)/2)*(a1-a2); a_k = m[b, 9k+3i+j, t, f]
//
// e-mapping: block = (b, 4-t chunk); thread tx owns flat elements
// e = 4tx..4tx+3 of the tile's (t,f) plane -> m loads are aligned float4
// (16 B/lane, perfectly coalesced). x window staged in LDS (swizzled).

constexpr int B = 8, C = 27, T = 1000, F = 257;
constexpr int TCH = 4;                 // t per tile (mult of 4 -> 16B-aligned m segs)
constexpr int NT  = T / TCH;           // 250 -> 2000 blocks
constexpr int BLK = 320;               // 5 waves
constexpr int NA  = 257;               // active compute lanes (float4s per segment)
constexpr int TROW = TCH + 2;          // staged t rows: t0-2 .. t0+3
constexpr int FP   = 260;              // x-plane row pitch (dwords)
constexpr int PLSZ = TROW * FP + 32;   // plane size + swizzle pad
constexpr size_t CS = (size_t)T * F;   // m channel stride (floats)

__device__ __forceinline__ int XSW(int a) { return a ^ (((a >> 5) & 7) << 2); }
__device__ __forceinline__ float comp(const float4& v, int r) {
    return r == 0 ? v.x : (r == 1 ? v.y : (r == 2 ? v.z : v.w));
}

__global__ __launch_bounds__(BLK, 3)
void ccm_kernel(const float* __restrict__ m,
                const float* __restrict__ x,
                float* __restrict__ out) {
    __shared__ float xs[2 * PLSZ];     // re plane, im plane (~12.7 KB)

    const int bid = blockIdx.x;
    const int tc  = bid % NT;
    const int b   = bid / NT;
    const int t0  = tc * TCH;
    const int tx  = threadIdx.x;

    const float* xb = x + (size_t)b * F * T * 2;

    // ---- stage x window: lane = fp (f+1), 6 t-values = 3 aligned float4 ----
    if (tx < 259) {
        const int f = tx - 1;                      // -1..257
        float vre[6], vim[6];
        #pragma unroll
        for (int tt = 0; tt < 6; ++tt) { vre[tt] = 0.f; vim[tt] = 0.f; }
        if (f >= 0 && f < F) {
            if (t0 >= 2) {                         // common case: 3 float4 loads
                const float4* src = reinterpret_cast<const float4*>(
                    xb + ((size_t)f * T + (t0 - 2)) * 2);
                const float4 p0 = src[0], p1 = src[1], p2 = src[2];
                vre[0] = p0.x; vim[0] = p0.y; vre[1] = p0.z; vim[1] = p0.w;
                vre[2] = p1.x; vim[2] = p1.y; vre[3] = p1.z; vim[3] = p1.w;
                vre[4] = p2.x; vim[4] = p2.y; vre[5] = p2.z; vim[5] = p2.w;
            } else {                               // first tile: zero-fill t<0
                #pragma unroll
                for (int tt = 0; tt < 6; ++tt) {
                    const int t = t0 - 2 + tt;
                    if (t >= 0) {
                        const float2 v2 = *reinterpret_cast<const float2*>(
                            xb + ((size_t)f * T + t) * 2);
                        vre[tt] = v2.x; vim[tt] = v2.y;
                    }
                }
            }
        }
        #pragma unroll
        for (int tt = 0; tt < 6; ++tt) {
            const int a = XSW(tt * FP + tx);
            xs[a]        = vre[tt];
            xs[PLSZ + a] = vim[tt];
        }
    }
    __syncthreads();

    if (tx >= NA) return;

    // ---- decode: e = 4tx..4tx+3 ; e = tl*257 + f ----
    const int e0 = 4 * tx;
    const int tl = e0 / 257;                       // 0..3
    const int f0 = e0 - tl * 257;                  // 0..256

    const float SQ3_2 = 0.8660254037844386f;
    const float* mseg = m + (size_t)b * C * CS + (size_t)t0 * F + 4 * tx;

    float4 g[9][3];
#define LOADG(n)                                                            \
    {                                                                       \
        g[n][0] = *reinterpret_cast<const float4*>(mseg + (size_t)(n) * CS);       \
        g[n][1] = *reinterpret_cast<const float4*>(mseg + (size_t)((n) + 9) * CS); \
        g[n][2] = *reinterpret_cast<const float4*>(mseg + (size_t)((n) + 18) * CS);\
    }

#define MAC_N(n, WRE, WIE)                                                  \
    {                                                                       \
        constexpr int i_ = (n) / 3, j_ = (n) % 3;                           \
        _Pragma("unroll")                                                   \
        for (int r = 0; r < 4; ++r) {                                       \
            const float a0 = comp(g[n][0], r);                              \
            const float a1 = comp(g[n][1], r);                              \
            const float a2 = comp(g[n][2], r);                              \
            const float hr = a0 - 0.5f * (a1 + a2);                         \
            const float hi = SQ3_2 * (a1 - a2);                             \
            accr[r] += hr * WRE(r, i_, j_) - hi * WIE(r, i_, j_);           \
            acci[r] += hr * WIE(r, i_, j_) + hi * WRE(r, i_, j_);           \
        }                                                                   \
    }

    float accr[4] = {0.f, 0.f, 0.f, 0.f};
    float acci[4] = {0.f, 0.f, 0.f, 0.f};

    LOADG(0); LOADG(1); LOADG(2);      // prime the pipeline (9 KB/wave in flight)

    if (f0 <= 253) {
        // fast path: all 4 positions at row tl, f = f0..f0+3
        // taps needed: rows tl..tl+2, fp = f0..f0+5 (pos r uses taps r..r+2)
        float wr[3][6], wi[3][6];
        #pragma unroll
        for (int i = 0; i < 3; ++i) {
            const int rowb = (tl + i) * FP + f0;
            #pragma unroll
            for (int k = 0; k < 6; ++k) {
                const int a = XSW(rowb + k);
                wr[i][k] = xs[a];
                wi[i][k] = xs[PLSZ + a];
            }
        }
#define WF_R(r, i, j) wr[i][(r) + (j)]
#define WF_I(r, i, j) wi[i][(r) + (j)]
        LOADG(3); MAC_N(0, WF_R, WF_I);
        LOADG(4); MAC_N(1, WF_R, WF_I);
        LOADG(5); MAC_N(2, WF_R, WF_I);
        LOADG(6); MAC_N(3, WF_R, WF_I);
        LOADG(7); MAC_N(4, WF_R, WF_I);
        LOADG(8); MAC_N(5, WF_R, WF_I);
        MAC_N(6, WF_R, WF_I);
        MAC_N(7, WF_R, WF_I);
        MAC_N(8, WF_R, WF_I);
#undef WF_R
#undef WF_I
    } else {
        // slow path (3 lanes/block): positions wrap the t boundary
        int tlr_[4], fr_[4];
        #pragma unroll
        for (int r = 0; r < 4; ++r) {
            const int w = (f0 + r) >= 257 ? 1 : 0;
            tlr_[r] = tl + w;
            fr_[r]  = f0 + r - 257 * w;
        }
#define WS_R(r, i, j) xs[XSW((tlr_[r] + (i)) * FP + fr_[r] + (j))]
#define WS_I(r, i, j) xs[PLSZ + XSW((tlr_[r] + (i)) * FP + fr_[r] + (j))]
        LOADG(3); MAC_N(0, WS_R, WS_I);
        LOADG(4); MAC_N(1, WS_R, WS_I);
        LOADG(5); MAC_N(2, WS_R, WS_I);
        LOADG(6); MAC_N(3, WS_R, WS_I);
        LOADG(7); MAC_N(4, WS_R, WS_I);
        LOADG(8); MAC_N(5, WS_R, WS_I);
        MAC_N(6, WS_R, WS_I);
        MAC_N(7, WS_R, WS_I);
        MAC_N(8, WS_R, WS_I);
#undef WS_R
#undef WS_I
    }
#undef LOADG
#undef MAC_N

    // ---- stores: 4 x float2; the 4 writers of each 32B sector share a block
    #pragma unroll
    for (int r = 0; r < 4; ++r) {
        const int w  = (f0 + r) >= 257 ? 1 : 0;
        const int fr = f0 + r - 257 * w;
        const int tr = t0 + tl + w;
        *reinterpret_cast<float2*>(out + ((size_t)(b * F + fr) * T + tr) * 2) =
            make_float2(accr[r], acci[r]);
    }
}

extern "C" void kernel_launch(void* const* d_in, const int* in_sizes, int n_in,
                              void* d_out, int out_size, void* d_ws, size_t ws_size,
                              hipStream_t stream) {
    const float* m = (const float*)d_in[0];
    const float* x = (const float*)d_in[1];
    // d_in[2] = v is a fixed compile-time constant per the reference.
    float* out = (float*)d_out;

    const int grid = B * NT;               // 2000 blocks
    ccm_kernel<<<grid, BLK, 0, stream>>>(m, x, out);
}